// Round 2
// baseline (80.120 us; speedup 1.0000x reference)
//
#include <hip/hip_runtime.h>

// Problem constants (B, I, C, U, S) = (256, 8, 1152, 10, 16)
#define B_DIM 256
#define I_DIM 8
#define C_DIM 1152
#define U_DIM 10
#define S_DIM 16
#define ROW (I_DIM * C_DIM)   // 9216 floats per batch element

// Single fused kernel, v2: 288 blocks x 256 threads, 4 capsules (c) per block.
// Round-1 lesson: fused v1 used 72 blocks -> only 72/256 CUs active; phase 1
// ran ~4x slower than the old standalone batch-reduce. v2 restores full-GPU
// parallelism (288 blocks = every CU busy, same thread count as the old k1)
// at the cost of 16 B-granular x loads (one float4 spans the block's 4 c's).
// Adjacent blocks consume the other quarters of each cache line concurrently;
// x (9.4 MB) is L3-resident, so HBM still reads each line once.
//
// Phase 1: xs[4][8] = sum_b x[b, i, c0..c0+3]. tid = bp*8 + i; each thread
//   sums 8 consecutive b (8 float4 loads, all in flight). LDS fold 32 -> 1.
// Phase 2: routing on tid<64 (c_local = tid>>4, s = tid&15), register
//   resident; W fragments (20 float4/thread) prefetched BEFORE phase 1 so
//   their HBM latency hides under the x reduction. Math identical to the
//   harness-verified 2-kernel version.
__global__ __launch_bounds__(256) void capsule_fused(
    const float* __restrict__ x, const float* __restrict__ W,
    float* __restrict__ out) {
  __shared__ float4 fold[32][I_DIM];     // [b_part][i], 4 KB
  __shared__ float xs_lds[4][I_DIM];

  const int tid = threadIdx.x;
  const int c0 = blockIdx.x * 4;
  const int c_local = tid >> 4;          // 0..3 (routing threads)
  const int s = tid & 15;                // 0..15

  // ---- W prefetch (routing threads only; issues before the x loads) ----
  // W float layout: ((c*U + u)*S + s)*I ; for fixed (c,s), u-stride = 128 floats.
  float4 wreg[U_DIM][2];
  if (tid < 64) {
    const float4* wp = (const float4*)(W +
        (size_t)(c0 + c_local) * (U_DIM * S_DIM * I_DIM) + s * I_DIM);
#pragma unroll
    for (int u = 0; u < U_DIM; ++u) {
      wreg[u][0] = wp[u * (S_DIM * I_DIM / 4)];
      wreg[u][1] = wp[u * (S_DIM * I_DIM / 4) + 1];
    }
  }

  // ---- Phase 1: batch-reduce x columns for this block's 4 capsules ----
  {
    const int bp = tid >> 3;             // 0..31
    const int i = tid & 7;               // 0..7
    const float* p = x + (size_t)(bp * 8) * ROW + i * C_DIM + c0;
    float4 acc = {0.f, 0.f, 0.f, 0.f};
#pragma unroll
    for (int j = 0; j < 8; ++j) {        // 8 loads, all in flight
      const float4 v = *(const float4*)(p + (size_t)j * ROW);
      acc.x += v.x; acc.y += v.y; acc.z += v.z; acc.w += v.w;
    }
    fold[bp][i] = acc;
  }
  __syncthreads();
  if (tid < 8) {                         // tid = i
    float4 a = fold[0][tid];
#pragma unroll
    for (int k = 1; k < 32; ++k) {
      const float4 v = fold[k][tid];
      a.x += v.x; a.y += v.y; a.z += v.z; a.w += v.w;
    }
    xs_lds[0][tid] = a.x;
    xs_lds[1][tid] = a.y;
    xs_lds[2][tid] = a.z;
    xs_lds[3][tid] = a.w;
  }
  __syncthreads();
  if (tid >= 64) return;                 // waves 1..3 done

  // ---- Phase 2: routing (identical math to the verified 2-kernel version) ----
  const int c = c0 + c_local;
  float xs[I_DIM];
#pragma unroll
  for (int i = 0; i < I_DIM; ++i) xs[i] = xs_lds[c_local][i];

  float us[U_DIM];
#pragma unroll
  for (int u = 0; u < U_DIM; ++u) {
    const float4 w0 = wreg[u][0], w1 = wreg[u][1];
    us[u] = w0.x * xs[0] + w0.y * xs[1] + w0.z * xs[2] + w0.w * xs[3] +
            w1.x * xs[4] + w1.y * xs[5] + w1.z * xs[6] + w1.w * xs[7];
  }

  float bij[U_DIM];
  float v[U_DIM];

  // iteration 0: softmax(0) == 1/10 exactly
#pragma unroll
  for (int u = 0; u < U_DIM; ++u) {
    const float sj = 0.1f * us[u];
    float msq = sj * sj;
#pragma unroll
    for (int w = 1; w < 16; w <<= 1) msq += __shfl_xor(msq, w);
    const float mag = sqrtf(msq);
    const float v0 = (msq / (1.f + msq)) * (sj / mag);
    v[u] = v0;
    float a = us[u] * v0;
#pragma unroll
    for (int w = 1; w < 16; w <<= 1) a += __shfl_xor(a, w);
    bij[u] = a * (1.f / (float)B_DIM);
  }

  // iterations 1..2: full softmax; last iteration skips the agreement update
#pragma unroll
  for (int it = 1; it < 3; ++it) {
    float m = bij[0];
#pragma unroll
    for (int u = 1; u < U_DIM; ++u) m = fmaxf(m, bij[u]);
    float e[U_DIM];
    float sum = 0.f;
#pragma unroll
    for (int u = 0; u < U_DIM; ++u) { e[u] = __expf(bij[u] - m); sum += e[u]; }
    const float inv = 1.f / sum;

#pragma unroll
    for (int u = 0; u < U_DIM; ++u) {
      const float sj = e[u] * inv * us[u];
      float msq = sj * sj;
#pragma unroll
      for (int w = 1; w < 16; w <<= 1) msq += __shfl_xor(msq, w);
      const float mag = sqrtf(msq);
      const float vv = (msq / (1.f + msq)) * (sj / mag);
      v[u] = vv;
      if (it < 2) {
        float a = us[u] * vv;
#pragma unroll
        for (int w = 1; w < 16; w <<= 1) a += __shfl_xor(a, w);
        bij[u] += a * (1.f / (float)B_DIM);
      }
    }
  }

#pragma unroll
  for (int u = 0; u < U_DIM; ++u)
    out[(size_t)c * (U_DIM * S_DIM) + u * S_DIM + s] = v[u];
}

extern "C" void kernel_launch(void* const* d_in, const int* in_sizes, int n_in,
                              void* d_out, int out_size, void* d_ws, size_t ws_size,
                              hipStream_t stream) {
  const float* x = (const float*)d_in[0];  // [256, 8, 1152]
  const float* W = (const float*)d_in[1];  // [1, 1152, 10, 16, 8]
  float* out = (float*)d_out;              // [1152, 10, 16]
  (void)d_ws; (void)ws_size;               // workspace unused

  capsule_fused<<<dim3(C_DIM / 4), 256, 0, stream>>>(x, W, out);
}

// Round 3
// 73.572 us; speedup vs baseline: 1.0890x; 1.0890x over previous
//
#include <hip/hip_runtime.h>

// Problem constants (B, I, C, U, S) = (256, 8, 1152, 10, 16)
#define B_DIM 256
#define I_DIM 8
#define C_DIM 1152
#define U_DIM 10
#define S_DIM 16
#define T_DIM (I_DIM * C_DIM)   // 9216 = flattened (i,c)
#define NCHUNK 8                // batch chunks for partial reduction

// Session verdict (R1/R2): fusing these two kernels into one dispatch was
// measured SLOWER both times (78.3 / 80.1 us vs 72.3/73.3 us for this
// structure), despite removing a launch gap and the 0.6 MB partial
// round-trip. The per-iteration time is dominated by the harness's 256 MiB
// workspace poison-fill (~43 us at ~80% HBM peak) plus ~25 us of fixed
// overhead that is insensitive to dispatch count. This 2-kernel structure is
// the measured best; keep it.

// Kernel 1: partial batch-reduce of x [B, I, C] -> partial [NCHUNK][T_DIM]
// Each block handles 256 consecutive t = i*C + c values; blockIdx.y = batch chunk.
// Fully coalesced: per b-iteration the block reads a contiguous 1 KB segment.
__global__ __launch_bounds__(256) void batch_reduce_kernel(
    const float* __restrict__ x, float* __restrict__ partial) {
    const int t = blockIdx.x * 256 + threadIdx.x;      // 0..9215
    const int k = blockIdx.y;                          // 0..7
    const float* p = x + (size_t)(k * (B_DIM / NCHUNK)) * T_DIM + t;
    float acc = 0.f;
#pragma unroll
    for (int b = 0; b < B_DIM / NCHUNK; ++b)
        acc += p[(size_t)b * T_DIM];
    partial[k * T_DIM + t] = acc;
}

// Kernel 2: 64-thread blocks, 4 capsules (c) per block -> 288 blocks spread
// across all 256 CUs. Chunk-partials are folded cooperatively through LDS
// (4 global loads/thread). Routing is register-resident; S=16 reductions via
// in-wave butterfly shuffles.
__global__ __launch_bounds__(64) void routing_kernel(
    const float* __restrict__ partial, const float* __restrict__ W,
    float* __restrict__ out) {
    __shared__ float foldbuf[2][32];
    __shared__ float xs_lds[32];                       // [c_local][i]

    const int tid = threadIdx.x;
    const int c0 = blockIdx.x * 4;

    // cooperative fold: partial[8][i*C + c] -> xs[c_local][i]
    {
        const int p = tid & 31;                        // p = c_local*8 + i
        const int grp = tid >> 5;                      // k-range [grp*4, grp*4+4)
        const int c_l = p >> 3, ii = p & 7;
        const float* pp = partial + (size_t)grp * 4 * T_DIM + ii * C_DIM + (c0 + c_l);
        float a = 0.f;
#pragma unroll
        for (int k = 0; k < 4; ++k) a += pp[(size_t)k * T_DIM];
        foldbuf[grp][p] = a;
    }
    __syncthreads();
    if (tid < 32) xs_lds[tid] = foldbuf[0][tid] + foldbuf[1][tid];
    __syncthreads();

    const int c_local = tid >> 4;                      // 0..3
    const int s = tid & 15;
    const int c = c0 + c_local;

    float xs[I_DIM];
#pragma unroll
    for (int i = 0; i < I_DIM; ++i) xs[i] = xs_lds[c_local * 8 + i];

    // u_sum[u] for this (c,s): dot(W[c,u,s,:], xs)   W contiguous in i (8 floats)
    float us[U_DIM];
#pragma unroll
    for (int u = 0; u < U_DIM; ++u) {
        const float4* w = (const float4*)(W + (((size_t)c * U_DIM + u) * S_DIM + s) * I_DIM);
        float4 w0 = w[0], w1 = w[1];
        us[u] = w0.x * xs[0] + w0.y * xs[1] + w0.z * xs[2] + w0.w * xs[3] +
                w1.x * xs[4] + w1.y * xs[5] + w1.z * xs[6] + w1.w * xs[7];
    }

    float bij[U_DIM];
    float v[U_DIM];

    // --- iteration 0: softmax(0) == 1/10 exactly; compute v and agreement ---
#pragma unroll
    for (int u = 0; u < U_DIM; ++u) {
        const float sj = 0.1f * us[u];
        float msq = sj * sj;
#pragma unroll
        for (int w = 1; w < 16; w <<= 1) msq += __shfl_xor(msq, w);
        const float mag = sqrtf(msq);
        const float v0 = (msq / (1.f + msq)) * (sj / mag);
        v[u] = v0;
        float a = us[u] * v0;
#pragma unroll
        for (int w = 1; w < 16; w <<= 1) a += __shfl_xor(a, w);
        bij[u] = a * (1.f / (float)B_DIM);
    }

    // --- iterations 1..2: full softmax; last iter skips agreement update ---
#pragma unroll
    for (int it = 1; it < 3; ++it) {
        float m = bij[0];
#pragma unroll
        for (int u = 1; u < U_DIM; ++u) m = fmaxf(m, bij[u]);
        float e[U_DIM];
        float sum = 0.f;
#pragma unroll
        for (int u = 0; u < U_DIM; ++u) { e[u] = __expf(bij[u] - m); sum += e[u]; }
        const float inv = 1.f / sum;

#pragma unroll
        for (int u = 0; u < U_DIM; ++u) {
            const float sj = e[u] * inv * us[u];
            float msq = sj * sj;
#pragma unroll
            for (int w = 1; w < 16; w <<= 1) msq += __shfl_xor(msq, w);
            const float mag = sqrtf(msq);
            const float vv = (msq / (1.f + msq)) * (sj / mag);
            v[u] = vv;
            if (it < 2) {
                float a = us[u] * vv;
#pragma unroll
                for (int w = 1; w < 16; w <<= 1) a += __shfl_xor(a, w);
                bij[u] += a * (1.f / (float)B_DIM);
            }
        }
    }

#pragma unroll
    for (int u = 0; u < U_DIM; ++u)
        out[(size_t)c * (U_DIM * S_DIM) + u * S_DIM + s] = v[u];
}

extern "C" void kernel_launch(void* const* d_in, const int* in_sizes, int n_in,
                              void* d_out, int out_size, void* d_ws, size_t ws_size,
                              hipStream_t stream) {
    const float* x = (const float*)d_in[0];   // [256, 8, 1152]
    const float* W = (const float*)d_in[1];   // [1, 1152, 10, 16, 8]
    float* out = (float*)d_out;               // [1152, 10, 16]
    float* partial = (float*)d_ws;            // [8][9216] = 294,912 bytes

    dim3 g1(T_DIM / 256, NCHUNK);             // 36 x 8 blocks
    batch_reduce_kernel<<<g1, 256, 0, stream>>>(x, partial);

    routing_kernel<<<C_DIM / 4, 64, 0, stream>>>(partial, W, out);
}

// Round 4
// 72.826 us; speedup vs baseline: 1.1002x; 1.0102x over previous
//
#include <hip/hip_runtime.h>

// Problem constants (B, I, C, U, S) = (256, 8, 1152, 10, 16)
#define B_DIM 256
#define I_DIM 8
#define C_DIM 1152
#define U_DIM 10
#define S_DIM 16
#define T_DIM (I_DIM * C_DIM)   // 9216 = flattened (i,c)
#define NCHUNK 32               // batch chunks for partial reduction (8 b each)

// Session verdict (R1/R2): single-dispatch fusion measured SLOWER both times
// (78.3 / 80.1 us vs 72.3-73.6 us for this 2-kernel structure). Per-iteration
// time is dominated by the harness's 256 MiB workspace poison-fill (~42 us at
// ~80% HBM peak) plus fixed overhead insensitive to dispatch count.
// R4 change: k1 loads vectorized float4 (256 B -> 1 KB per wave-instruction,
// 2.36M -> 590K load instrs) at same thread/block count via NCHUNK 8 -> 32.

// Kernel 1: partial batch-reduce of x [B, I, C] -> partial [NCHUNK][T_DIM]
// Thread handles one float4 of t (4 consecutive t); blockIdx.y = batch chunk
// (8 consecutive b). Per b-iteration a wave reads a contiguous 1 KB segment.
__global__ __launch_bounds__(256) void batch_reduce_kernel(
    const float* __restrict__ x, float* __restrict__ partial) {
    const int t4 = blockIdx.x * 256 + threadIdx.x;     // 0..2303
    const int k = blockIdx.y;                          // 0..31
    const float* p = x + (size_t)(k * (B_DIM / NCHUNK)) * T_DIM + t4 * 4;
    float4 acc = {0.f, 0.f, 0.f, 0.f};
#pragma unroll
    for (int b = 0; b < B_DIM / NCHUNK; ++b) {         // 8 float4 loads in flight
        const float4 v = *(const float4*)(p + (size_t)b * T_DIM);
        acc.x += v.x; acc.y += v.y; acc.z += v.z; acc.w += v.w;
    }
    *(float4*)(partial + (size_t)k * T_DIM + t4 * 4) = acc;
}

// Kernel 2: 64-thread blocks, 4 capsules (c) per block -> 288 blocks spread
// across all 256 CUs. Chunk-partials folded cooperatively through LDS
// (16 global loads/thread). Routing is register-resident; S=16 reductions via
// in-wave butterfly shuffles.
__global__ __launch_bounds__(64) void routing_kernel(
    const float* __restrict__ partial, const float* __restrict__ W,
    float* __restrict__ out) {
    __shared__ float foldbuf[2][32];
    __shared__ float xs_lds[32];                       // [c_local][i]

    const int tid = threadIdx.x;
    const int c0 = blockIdx.x * 4;

    // cooperative fold: partial[32][i*C + c] -> xs[c_local][i]
    {
        const int p = tid & 31;                        // p = c_local*8 + i
        const int grp = tid >> 5;                      // chunk range [grp*16, +16)
        const int c_l = p >> 3, ii = p & 7;
        const float* pp = partial + (size_t)grp * 16 * T_DIM + ii * C_DIM + (c0 + c_l);
        float a = 0.f;
#pragma unroll
        for (int k = 0; k < 16; ++k) a += pp[(size_t)k * T_DIM];
        foldbuf[grp][p] = a;
    }
    __syncthreads();
    if (tid < 32) xs_lds[tid] = foldbuf[0][tid] + foldbuf[1][tid];
    __syncthreads();

    const int c_local = tid >> 4;                      // 0..3
    const int s = tid & 15;
    const int c = c0 + c_local;

    float xs[I_DIM];
#pragma unroll
    for (int i = 0; i < I_DIM; ++i) xs[i] = xs_lds[c_local * 8 + i];

    // u_sum[u] for this (c,s): dot(W[c,u,s,:], xs)   W contiguous in i (8 floats)
    float us[U_DIM];
#pragma unroll
    for (int u = 0; u < U_DIM; ++u) {
        const float4* w = (const float4*)(W + (((size_t)c * U_DIM + u) * S_DIM + s) * I_DIM);
        float4 w0 = w[0], w1 = w[1];
        us[u] = w0.x * xs[0] + w0.y * xs[1] + w0.z * xs[2] + w0.w * xs[3] +
                w1.x * xs[4] + w1.y * xs[5] + w1.z * xs[6] + w1.w * xs[7];
    }

    float bij[U_DIM];
    float v[U_DIM];

    // --- iteration 0: softmax(0) == 1/10 exactly; compute v and agreement ---
#pragma unroll
    for (int u = 0; u < U_DIM; ++u) {
        const float sj = 0.1f * us[u];
        float msq = sj * sj;
#pragma unroll
        for (int w = 1; w < 16; w <<= 1) msq += __shfl_xor(msq, w);
        const float mag = sqrtf(msq);
        const float v0 = (msq / (1.f + msq)) * (sj / mag);
        v[u] = v0;
        float a = us[u] * v0;
#pragma unroll
        for (int w = 1; w < 16; w <<= 1) a += __shfl_xor(a, w);
        bij[u] = a * (1.f / (float)B_DIM);
    }

    // --- iterations 1..2: full softmax; last iter skips agreement update ---
#pragma unroll
    for (int it = 1; it < 3; ++it) {
        float m = bij[0];
#pragma unroll
        for (int u = 1; u < U_DIM; ++u) m = fmaxf(m, bij[u]);
        float e[U_DIM];
        float sum = 0.f;
#pragma unroll
        for (int u = 0; u < U_DIM; ++u) { e[u] = __expf(bij[u] - m); sum += e[u]; }
        const float inv = 1.f / sum;

#pragma unroll
        for (int u = 0; u < U_DIM; ++u) {
            const float sj = e[u] * inv * us[u];
            float msq = sj * sj;
#pragma unroll
            for (int w = 1; w < 16; w <<= 1) msq += __shfl_xor(msq, w);
            const float mag = sqrtf(msq);
            const float vv = (msq / (1.f + msq)) * (sj / mag);
            v[u] = vv;
            if (it < 2) {
                float a = us[u] * vv;
#pragma unroll
                for (int w = 1; w < 16; w <<= 1) a += __shfl_xor(a, w);
                bij[u] += a * (1.f / (float)B_DIM);
            }
        }
    }

#pragma unroll
    for (int u = 0; u < U_DIM; ++u)
        out[(size_t)c * (U_DIM * S_DIM) + u * S_DIM + s] = v[u];
}

extern "C" void kernel_launch(void* const* d_in, const int* in_sizes, int n_in,
                              void* d_out, int out_size, void* d_ws, size_t ws_size,
                              hipStream_t stream) {
    const float* x = (const float*)d_in[0];   // [256, 8, 1152]
    const float* W = (const float*)d_in[1];   // [1, 1152, 10, 16, 8]
    float* out = (float*)d_out;               // [1152, 10, 16]
    float* partial = (float*)d_ws;            // [32][9216] = 1,179,648 bytes

    dim3 g1(T_DIM / (256 * 4), NCHUNK);       // 9 x 32 blocks, 288 total
    batch_reduce_kernel<<<g1, 256, 0, stream>>>(x, partial);

    routing_kernel<<<C_DIM / 4, 64, 0, stream>>>(partial, W, out);
}